// Round 11
// baseline (393.086 us; speedup 1.0000x reference)
//
#include <hip/hip_runtime.h>

#define N_DB   100000
#define B_Q    1024
#define D_F    64
#define K_NN   100
#define JITTER 1e-6f
#define NS     12544   // prefix-sample cols = 98*128
#define STGT   40      // sample cum target (1/8 sample -> full count >= 100 w.h.p.)
#define NT     782     // n-tiles = ceil(N_DB/128)
#define SLOT   16      // per-(tile,row) candidate slots
#define CAP    3072    // per-row dense candidate capacity
#define BB     512     // boundary-bin capacity in k_rank
#define TP     80      // padded LDS k-stride (bf16 elems)
#define AST    68      // k_regress LDS row stride (f32)

typedef __attribute__((ext_vector_type(8))) short bf16x8;
typedef __attribute__((ext_vector_type(4))) float f32x4;

__device__ __forceinline__ unsigned short f2b(float x) {   // f32 -> bf16 RNE
    unsigned u = __float_as_uint(x);
    u += 0x7FFF + ((u >> 16) & 1);
    return (unsigned short)(u >> 16);
}

// ---------------- fused bf16 copy + squared norms (16 lanes/row) ----------------
__global__ __launch_bounds__(256) void k_prep(
    const float* __restrict__ db_X, const float* __restrict__ input,
    unsigned short* __restrict__ dbb, unsigned short* __restrict__ inb,
    float* __restrict__ d2, float* __restrict__ x2) {
    int tid = threadIdx.x;
    int lane = tid & 63;
    int sub = lane & 15, grp = lane >> 4;
    int row = blockIdx.x * 16 + (tid >> 6) * 4 + grp;
    const int R = N_DB + B_Q;
    if (row >= R) return;
    const float* src = (row < N_DB) ? db_X + (size_t)row * 64 + sub * 4
                                    : input + (size_t)(row - N_DB) * 64 + sub * 4;
    unsigned short* dst = (row < N_DB) ? dbb + (size_t)row * 64 + sub * 4
                                       : inb + (size_t)(row - N_DB) * 64 + sub * 4;
    float4 w = *(const float4*)src;
    ushort4 o = { f2b(w.x), f2b(w.y), f2b(w.z), f2b(w.w) };
    *(ushort4*)dst = o;
    float s = w.x * w.x + w.y * w.y + w.z * w.z + w.w * w.w;
    s += __shfl_xor(s, 1, 64);
    s += __shfl_xor(s, 2, 64);
    s += __shfl_xor(s, 4, 64);
    s += __shfl_xor(s, 8, 64);
    if (sub == 0) {
        if (row < N_DB) d2[row] = s;
        else            x2[row - N_DB] = s;
    }
}

// ---------------- bf16 tile staging (from preconverted arrays) ----------------
__device__ __forceinline__ void stage_rows_bf16(
    const unsigned short* __restrict__ src, unsigned short* dst,
    int n0, int tid, bool guard) {
    #pragma unroll
    for (int it = 0; it < 4; it++) {               // 1024 short8 = 128 rows x 8 chunks
        int f = it * 256 + tid;
        int c = f >> 3, k8 = f & 7;
        int n = n0 + c;
        uint4 w = make_uint4(0u, 0u, 0u, 0u);
        if (!guard || n < N_DB) w = *(const uint4*)(src + (size_t)n * 64 + k8 * 8);
        *(uint4*)(&dst[c * TP + k8 * 8]) = w;
    }
}

__device__ __forceinline__ void mfma_tile(
    const unsigned short* As, const unsigned short* Bs,
    int wr, int wc, int fr, int fq, f32x4 acc[4][4]) {
    #pragma unroll
    for (int ks = 0; ks < 2; ks++) {
        int koff = fq * 8 + ks * 32;
        bf16x8 a[4], b[4];
        #pragma unroll
        for (int i = 0; i < 4; i++)
            a[i] = *(const bf16x8*)(&As[(wr + i * 16 + fr) * TP + koff]);
        #pragma unroll
        for (int j = 0; j < 4; j++)
            b[j] = *(const bf16x8*)(&Bs[(wc + j * 16 + fr) * TP + koff]);
        #pragma unroll
        for (int i = 0; i < 4; i++)
            #pragma unroll
            for (int j = 0; j < 4; j++)
                acc[i][j] = __builtin_amdgcn_mfma_f32_16x16x32_bf16(a[i], b[j], acc[i][j], 0, 0, 0);
    }
}

// ---------------- sample GEMM -> byte bins (2D grid, coalesced u32 stores) ----------------
__global__ __launch_bounds__(256) void k_gemm_sample(
    const unsigned short* __restrict__ inb, const unsigned short* __restrict__ dbb,
    const float* __restrict__ x2, const float* __restrict__ d2,
    unsigned char* __restrict__ sbin) {
    __shared__ unsigned short As[128 * TP];
    __shared__ unsigned short Bs[128 * TP];
    __shared__ float x2s[128], d2s[128];
    int tid = threadIdx.x;
    int n0 = blockIdx.x * 128;                     // < NS
    int b0 = blockIdx.y * 128;

    stage_rows_bf16(dbb, Bs, n0, tid, false);
    stage_rows_bf16(inb, As, b0, tid, false);
    if (tid < 128) {
        d2s[tid] = d2[n0 + tid];
        x2s[tid] = x2[b0 + tid];
    }
    __syncthreads();

    int lane = tid & 63, wid = tid >> 6;
    int wr = (wid >> 1) * 64, wc = (wid & 1) * 64;
    int fr = lane & 15, fq = lane >> 4;
    f32x4 acc[4][4];
    #pragma unroll
    for (int i = 0; i < 4; i++)
        #pragma unroll
        for (int j = 0; j < 4; j++) acc[i][j] = (f32x4){0.f, 0.f, 0.f, 0.f};
    mfma_tile(As, Bs, wr, wc, fr, fq, acc);

    const float inv_d = 1.0f / D_F;
    int jsel = fr >> 2;
    int base_src = (fq << 4) | (4 * (fr & 3));
    #pragma unroll
    for (int i = 0; i < 4; i++) {
        #pragma unroll
        for (int r = 0; r < 4; r++) {
            int row = wr + i * 16 + fq * 4 + r;    // C/D: col=lane&15, row=(lane>>4)*4+reg
            float xx = x2s[row];
            unsigned p = 0;
            #pragma unroll
            for (int j = 0; j < 4; j++) {
                int col = wc + j * 16 + fr;
                float dv = (xx + d2s[col] - 2.0f * acc[i][j][r]) * inv_d;
                int bin = (int)(dv * 64.0f);
                bin = bin < 0 ? 0 : (bin > 255 ? 255 : bin);
                p |= (unsigned)bin << (8 * j);
            }
            unsigned out = 0;
            #pragma unroll
            for (int e = 0; e < 4; e++) {
                unsigned q = __shfl(p, base_src + e, 64);
                out |= ((q >> (8 * jsel)) & 255u) << (8 * e);
            }
            int ncol = n0 + wc + 4 * fr;
            *(unsigned*)(sbin + (size_t)(b0 + row) * NS + ncol) = out;
        }
    }
}

// ---------------- per-row sample histogram -> threshold bin ----------------
__global__ __launch_bounds__(256) void k_thr(
    const unsigned char* __restrict__ sbin, int* __restrict__ thr_t) {
    int b = blockIdx.x, tid = threadIdx.x;
    __shared__ int hist[256];
    hist[tid] = 0;
    __syncthreads();
    const uint4* row4 = (const uint4*)(sbin + (size_t)b * NS);
    for (int v = tid; v < NS / 16; v += 256) {
        uint4 w = row4[v];
        unsigned ws[4] = {w.x, w.y, w.z, w.w};
        #pragma unroll
        for (int q = 0; q < 4; q++)
            #pragma unroll
            for (int e = 0; e < 4; e++)
                atomicAdd(&hist[(ws[q] >> (8 * e)) & 255u], 1);
    }
    __syncthreads();
    if (tid == 0) {
        int cum = 0, t = 255;
        for (int i = 0; i < 256; i++) {
            cum += hist[i];
            if (cum >= STGT) { t = i; break; }
        }
        thr_t[b] = t;
    }
}

// ---------------- full GEMM -> per-(tile,row) slots, ZERO global atomics ----------------
__global__ __launch_bounds__(256) void k_gemm_cand(
    const unsigned short* __restrict__ inb, const unsigned short* __restrict__ dbb,
    const float* __restrict__ x2, const float* __restrict__ d2,
    const int* __restrict__ thr_t, unsigned char* __restrict__ counts,
    unsigned char* __restrict__ nle2, unsigned* __restrict__ cand2) {
    __shared__ unsigned short As[128 * TP];
    __shared__ unsigned short Bs[128 * TP];
    __shared__ float d2h[128], rl[128], rt[128];
    __shared__ int rowcnt[128], rtc[128];
    __shared__ unsigned slots[128 * SLOT];
    int tid = threadIdx.x;
    int n0 = blockIdx.x * 128;
    int b0 = blockIdx.y * 128;

    stage_rows_bf16(dbb, Bs, n0, tid, true);
    stage_rows_bf16(inb, As, b0, tid, false);
    if (tid < 128) {
        int n = n0 + tid;
        d2h[tid] = (n < N_DB) ? d2[n] * 0.5f : 1e30f;  // pad cols can never hit
        float xx = x2[b0 + tid];
        int t = thr_t[b0 + tid];
        rl[tid] = (xx - (float)(t + 3)) * 0.5f;
        rt[tid] = (xx - (float)(t + 1)) * 0.5f;
        rowcnt[tid] = 0; rtc[tid] = 0;
    }
    __syncthreads();

    int lane = tid & 63, wid = tid >> 6;
    int wr = (wid >> 1) * 64, wc = (wid & 1) * 64;
    int fr = lane & 15, fq = lane >> 4;
    f32x4 acc[4][4];
    #pragma unroll
    for (int i = 0; i < 4; i++)
        #pragma unroll
        for (int j = 0; j < 4; j++) acc[i][j] = (f32x4){0.f, 0.f, 0.f, 0.f};
    mfma_tile(As, Bs, wr, wc, fr, fq, acc);

    #pragma unroll
    for (int i = 0; i < 4; i++) {
        #pragma unroll
        for (int r = 0; r < 4; r++) {
            int row = wr + i * 16 + fq * 4 + r;
            float rlv = rl[row], rtv = rt[row];
            #pragma unroll
            for (int j = 0; j < 4; j++) {
                int col = wc + j * 16 + fr;
                float a = acc[i][j][r];
                float dh = d2h[col];
                if (a > rlv + dh) {                // loose hit (superset)
                    int pos = atomicAdd(&rowcnt[row], 1);      // LDS atomic only
                    if (pos < SLOT) slots[row * SLOT + pos] = (unsigned)(n0 + col);
                    if (a > rtv + dh) atomicAdd(&rtc[row], 1); // tight
                }
            }
        }
    }
    __syncthreads();

    size_t gb = (size_t)blockIdx.x * B_Q + b0;
    if (tid < 128) {
        int rc = rowcnt[tid]; counts[gb + tid] = (unsigned char)(rc > 255 ? 255 : rc);
        int tc = rtc[tid];    nle2[gb + tid]   = (unsigned char)(tc > 255 ? 255 : tc);
    }
    for (int e = tid; e < 128 * SLOT; e += 256)
        cand2[gb * SLOT + e] = slots[e];           // 8KB contiguous per block
}

// ---------------- compact slots -> dense list + exact f32 distances ----------------
__global__ __launch_bounds__(256) void k_refine(
    const unsigned char* __restrict__ counts, const unsigned char* __restrict__ nle2,
    const unsigned* __restrict__ cand2, const float* __restrict__ input,
    const float* __restrict__ db_X, const float* __restrict__ x2,
    const float* __restrict__ d2, float* __restrict__ cdG, int* __restrict__ ciG,
    int* __restrict__ cntF, int* __restrict__ nleF, int* __restrict__ badF) {
    int b = blockIdx.x, tid = threadIdx.x, lane = tid & 63;
    __shared__ float xrow[64];
    __shared__ int lidx[CAP];
    __shared__ int s_cnt, s_nle, s_bad;
    if (tid < 64) xrow[tid] = input[(size_t)b * 64 + tid];
    if (tid == 0) { s_cnt = 0; s_nle = 0; s_bad = 0; }
    __syncthreads();

    int tight = 0, bad = 0;
    for (int t = tid; t < NT; t += 256) {
        int c = counts[(size_t)t * B_Q + b];
        tight += nle2[(size_t)t * B_Q + b];
        if (c > SLOT) { bad = 1; c = SLOT; }
        const unsigned* sp = cand2 + ((size_t)t * B_Q + b) * SLOT;
        for (int e = 0; e < c; e++) {
            int pos = atomicAdd(&s_cnt, 1);
            if (pos < CAP) lidx[pos] = (int)sp[e];
            else bad = 1;
        }
    }
    #pragma unroll
    for (int off = 32; off; off >>= 1) tight += __shfl_xor(tight, off, 64);
    if (lane == 0) atomicAdd(&s_nle, tight);
    if (bad) atomicOr(&s_bad, 1);
    __syncthreads();

    int cn = s_cnt > CAP ? CAP : s_cnt;
    float xx = x2[b];
    for (int c = tid; c < cn; c += 256) {
        int n = lidx[c];
        const float4* dr = (const float4*)(db_X + (size_t)n * D_F);
        float dot = 0.f;
        #pragma unroll
        for (int k = 0; k < 16; k++) {
            float4 w = dr[k];
            dot += xrow[k * 4 + 0] * w.x + xrow[k * 4 + 1] * w.y
                 + xrow[k * 4 + 2] * w.z + xrow[k * 4 + 3] * w.w;
        }
        cdG[(size_t)b * CAP + c] = (xx - 2.0f * dot + d2[n]) * (1.0f / D_F);
        ciG[(size_t)b * CAP + c] = n;
    }
    if (tid == 0) {
        cntF[b] = cn;
        nleF[b] = s_nle;
        badF[b] = s_bad;
    }
}

// ---------------- exact top-100 via fine histogram + boundary mini-rank ----------------
__global__ __launch_bounds__(256) void k_rank(
    const int* __restrict__ cntF, const int* __restrict__ nleF,
    const int* __restrict__ badF, const float* __restrict__ cdG,
    const int* __restrict__ ciG, const int* __restrict__ thr_t,
    const float* __restrict__ input, const float* __restrict__ db_X,
    const float* __restrict__ x2, const float* __restrict__ d2,
    int* __restrict__ idx) {
    int b = blockIdx.x, tid = threadIdx.x;
    __shared__ float ldist[CAP];
    __shared__ int lidx[CAP];
    __shared__ int hist[1024];
    __shared__ int s4[256];
    __shared__ float bbd[BB];
    __shared__ int bbn[BB];
    __shared__ int s_b100, s_c0, s_out, s_bb;
    __shared__ float xrow[64];

    if (tid < 64) xrow[tid] = input[(size_t)b * 64 + tid];
    #pragma unroll
    for (int h = 0; h < 4; h++) hist[h * 256 + tid] = 0;
    if (tid == 0) { s_out = 0; s_bb = 0; }
    __syncthreads();

    int cn = cntF[b];
    bool bad = (badF[b] != 0) || (nleF[b] < K_NN);
    float xx = x2[b];

    float sc;
    if (!bad) {
        float hi = (float)(thr_t[b] + 4) * (1.0f / 64.0f);
        sc = 1024.0f / hi;
        for (int c = tid; c < cn; c += 256) {
            float d = cdG[(size_t)b * CAP + c];
            ldist[c] = d;
            lidx[c] = ciG[(size_t)b * CAP + c];
            int bn = (int)(d * sc);
            bn = bn < 0 ? 0 : (bn > 1023 ? 1023 : bn);
            atomicAdd(&hist[bn], 1);
        }
    } else {
        sc = 256.0f;
        for (int n = tid; n < N_DB; n += 256) {
            const float4* dr = (const float4*)(db_X + (size_t)n * D_F);
            float dot = 0.f;
            #pragma unroll
            for (int k = 0; k < 16; k++) {
                float4 w = dr[k];
                dot += xrow[k * 4 + 0] * w.x + xrow[k * 4 + 1] * w.y
                     + xrow[k * 4 + 2] * w.z + xrow[k * 4 + 3] * w.w;
            }
            float d = (xx - 2.0f * dot + d2[n]) * (1.0f / D_F);
            int bn = (int)(d * sc);
            bn = bn < 0 ? 0 : (bn > 1023 ? 1023 : bn);
            atomicAdd(&hist[bn], 1);
        }
    }
    __syncthreads();

    {
        int t4 = hist[4 * tid] + hist[4 * tid + 1] + hist[4 * tid + 2] + hist[4 * tid + 3];
        s4[tid] = t4;
    }
    __syncthreads();
    if (tid == 0) {
        int cum = 0, bsel = 1023, c0 = 0;
        for (int g = 0; g < 256; g++) {
            if (cum + s4[g] >= K_NN) {
                int c2 = cum;
                bsel = g * 4 + 3;
                for (int e = 0; e < 4; e++) {
                    if (c2 + hist[g * 4 + e] >= K_NN) { bsel = g * 4 + e; break; }
                    c2 += hist[g * 4 + e];
                }
                c0 = c2;
                break;
            }
            cum += s4[g];
        }
        s_b100 = bsel; s_c0 = c0;
    }
    __syncthreads();
    int b100 = s_b100, c0 = s_c0;      // c0 < 100 entries strictly below bin b100

    if (!bad) {
        for (int c = tid; c < cn; c += 256) {
            float d = ldist[c];
            int bn = (int)(d * sc);
            bn = bn < 0 ? 0 : (bn > 1023 ? 1023 : bn);
            if (bn < b100) {
                int pos = atomicAdd(&s_out, 1);
                idx[(size_t)b * K_NN + pos] = lidx[c];
            } else if (bn == b100) {
                int pos = atomicAdd(&s_bb, 1);
                if (pos < BB) { bbd[pos] = d; bbn[pos] = lidx[c]; }
            }
        }
    } else {
        for (int n = tid; n < N_DB; n += 256) {
            const float4* dr = (const float4*)(db_X + (size_t)n * D_F);
            float dot = 0.f;
            #pragma unroll
            for (int k = 0; k < 16; k++) {
                float4 w = dr[k];
                dot += xrow[k * 4 + 0] * w.x + xrow[k * 4 + 1] * w.y
                     + xrow[k * 4 + 2] * w.z + xrow[k * 4 + 3] * w.w;
            }
            float d = (xx - 2.0f * dot + d2[n]) * (1.0f / D_F);
            int bn = (int)(d * sc);
            bn = bn < 0 ? 0 : (bn > 1023 ? 1023 : bn);
            if (bn < b100) {
                int pos = atomicAdd(&s_out, 1);
                idx[(size_t)b * K_NN + pos] = n;
            } else if (bn == b100) {
                int pos = atomicAdd(&s_bb, 1);
                if (pos < BB) { bbd[pos] = d; bbn[pos] = n; }
            }
        }
    }
    __syncthreads();

    int m = K_NN - c0;
    int bc = s_bb; if (bc > BB) bc = BB;
    for (int c = tid; c < bc; c += 256) {
        float dc = bbd[c]; int nc = bbn[c];
        int rank = 0;
        for (int j = 0; j < bc; j++) {
            float dj = bbd[j];
            rank += (dj < dc) || (dj == dc && bbn[j] < nc);
        }
        if (rank < m) {
            int pos = atomicAdd(&s_out, 1);
            idx[(size_t)b * K_NN + pos] = nc;
        }
    }
}

// ---------------- per-row regression + loss ----------------
// symmetric AtA (153 tiles) + Aty on wave 3; rank-4 blocked GE with TRUE multipliers
// (17 rounds x 2 barriers); wave back-sub; parallel pred.
__global__ __launch_bounds__(256) void k_regress(
    const float* __restrict__ input, const float* __restrict__ target,
    const float* __restrict__ db_X, const float* __restrict__ db_y,
    const int* __restrict__ idx, float* __restrict__ out) {
    int b = blockIdx.x, tid = threadIdx.x;
    int lane = tid & 63, wid = tid >> 6;
    __shared__ float A[K_NN * AST];      // [k][p], col0 = 1, cols 65..67 = 0
    __shared__ float M[65 * AST];        // cols 0..64 AtA, col 65 = Aty (augmented)
    __shared__ float v[65], xa[68];
    __shared__ float yv[K_NN];
    __shared__ int nbr[K_NN];
    __shared__ float s_inv[4];

    if (tid < K_NN) {
        int n = idx[(size_t)b * K_NN + tid];
        nbr[tid] = n;
        yv[tid] = db_y[n];
    }
    if (tid < 64) xa[1 + tid] = input[(size_t)b * D_F + tid];
    if (tid == 0) { xa[0] = 1.f; xa[65] = xa[66] = xa[67] = 0.f; }
    __syncthreads();

    // stage A = [1 | Xn] rows; zero pad cols 65..67
    for (int f = tid; f < K_NN * 16; f += 256) {
        int k = f >> 4, q = f & 15;
        float4 w = *(const float4*)(db_X + (size_t)nbr[k] * D_F + q * 4);
        A[k * AST + 1 + q * 4 + 0] = w.x;
        A[k * AST + 1 + q * 4 + 1] = w.y;
        A[k * AST + 1 + q * 4 + 2] = w.z;
        A[k * AST + 1 + q * 4 + 3] = w.w;
    }
    if (tid < K_NN) {
        A[tid * AST + 0] = 1.0f;
        A[tid * AST + 65] = 0.f; A[tid * AST + 66] = 0.f; A[tid * AST + 67] = 0.f;
    }
    __syncthreads();

    // symmetric AtA: upper-triangle 4x4 tiles (153 tasks, waves 0-2); Aty on wave 3
    if (tid < 153) {
        int ti = 0, rem = tid;
        while (rem >= 17 - ti) { rem -= 17 - ti; ti++; }
        int tj = ti + rem;
        int p0 = ti * 4, q0 = tj * 4;
        float acc[4][4];
        #pragma unroll
        for (int ii = 0; ii < 4; ii++)
            #pragma unroll
            for (int jj = 0; jj < 4; jj++) acc[ii][jj] = 0.f;
        for (int k = 0; k < K_NN; k++) {
            float4 ap = *(const float4*)(&A[k * AST + p0]);
            float4 aq = *(const float4*)(&A[k * AST + q0]);
            float app[4] = {ap.x, ap.y, ap.z, ap.w};
            float aqq[4] = {aq.x, aq.y, aq.z, aq.w};
            #pragma unroll
            for (int ii = 0; ii < 4; ii++)
                #pragma unroll
                for (int jj = 0; jj < 4; jj++) acc[ii][jj] += app[ii] * aqq[jj];
        }
        #pragma unroll
        for (int ii = 0; ii < 4; ii++)
            #pragma unroll
            for (int jj = 0; jj < 4; jj++) {
                int p = p0 + ii, q = q0 + jj;
                if (p < 65 && q < 65) {
                    float val = acc[ii][jj] + (p == q ? JITTER : 0.f);
                    M[p * AST + q] = val;
                    if (ti != tj) M[q * AST + p] = val;   // mirror
                }
            }
    } else if (tid >= 192) {
        int p = tid - 192;                                // wave 3: p = 0..63
        float s = 0.f;
        for (int k = 0; k < K_NN; k++) s += A[k * AST + p] * yv[k];
        M[p * AST + 65] = s;
        if (tid == 192) {                                 // p = 64
            float s2 = 0.f;
            for (int k = 0; k < K_NN; k++) s2 += A[k * AST + 64] * yv[k];
            M[64 * AST + 65] = s2;
        }
    }
    __syncthreads();

    // rank-4 blocked GE, 17 rounds. Panel (wave 0) factors the 4-row band.
    // Trailing: per row i >= jend, reconstruct TRUE multipliers a0..a3 via the
    // in-band correction chain (bit-identical to sequential elimination), then
    // rank-4 update of cols >= jend incl. RHS. Lower triangle left stale (unused).
    for (int jb = 0; jb < 17; jb++) {
        int j0 = jb * 4;
        int jend = (j0 + 4 < 65) ? j0 + 4 : 65;
        int np = jend - j0;                               // 4, or 1 in last round
        if (wid == 0) {
            #pragma unroll
            for (int l4 = 0; l4 < 4; l4++) {
                int l = j0 + l4;
                if (l4 < np) {
                    float inv = 1.0f / M[l * AST + l];
                    if (lane == 0) s_inv[l4] = inv;
                    for (int i = l + 1; i < jend; i++) {
                        float mil = M[i * AST + l] * inv;
                        for (int c = l + 1 + lane; c < 66; c += 64)
                            M[i * AST + c] -= mil * M[l * AST + c];
                    }
                }
            }
        }
        __syncthreads();
        float inv0 = s_inv[0], inv1 = s_inv[1], inv2 = s_inv[2], inv3 = s_inv[3];
        for (int i = jend + (tid >> 6); i < 65; i += 4) {
            float a0 = M[i * AST + j0] * inv0;
            float a1 = 0.f, a2 = 0.f, a3 = 0.f;
            if (np > 1)
                a1 = (M[i * AST + j0 + 1] - a0 * M[j0 * AST + j0 + 1]) * inv1;
            if (np > 2)
                a2 = (M[i * AST + j0 + 2] - a0 * M[j0 * AST + j0 + 2]
                                          - a1 * M[(j0 + 1) * AST + j0 + 2]) * inv2;
            if (np > 3)
                a3 = (M[i * AST + j0 + 3] - a0 * M[j0 * AST + j0 + 3]
                                          - a1 * M[(j0 + 1) * AST + j0 + 3]
                                          - a2 * M[(j0 + 2) * AST + j0 + 3]) * inv3;
            for (int c = jend + lane; c < 66; c += 64) {
                float m = M[i * AST + c];
                m -= a0 * M[j0 * AST + c];
                if (np > 1) m -= a1 * M[(j0 + 1) * AST + c];
                if (np > 2) m -= a2 * M[(j0 + 2) * AST + c];
                if (np > 3) m -= a3 * M[(j0 + 3) * AST + c];
                M[i * AST + c] = m;
            }
        }
        __syncthreads();
    }

    // back-substitution: single wave, barrier-free
    if (tid < 64) {
        int i = tid;
        float ri = M[i * AST + 65];
        float di = M[i * AST + i];
        float x64 = M[64 * AST + 65] / M[64 * AST + 64];
        ri -= M[i * AST + 64] * x64;
        float xi_out = 0.f;
        for (int j = 63; j >= 0; j--) {
            float xj = __shfl(ri, j, 64) / __shfl(di, j, 64);
            if (i == j) xi_out = xj;
            if (i < j) ri -= M[i * AST + j] * xj;
        }
        v[i] = xi_out;
        if (i == 0) v[64] = x64;
    }
    __syncthreads();

    // parallel pred + loss (wave 0)
    if (wid == 0) {
        float p = xa[lane] * v[lane];
        if (lane == 0) p += xa[64] * v[64];
        #pragma unroll
        for (int off = 32; off; off >>= 1) p += __shfl_xor(p, off, 64);
        if (lane == 0) {
            float e = p - target[b];
            atomicAdd(out, e * e * (1.0f / B_Q));
        }
    }
}

extern "C" void kernel_launch(void* const* d_in, const int* in_sizes, int n_in,
                              void* d_out, int out_size, void* d_ws, size_t ws_size,
                              hipStream_t stream) {
    const float* input  = (const float*)d_in[0];
    const float* target = (const float*)d_in[1];
    const float* db_X   = (const float*)d_in[2];
    const float* db_y   = (const float*)d_in[3];
    float* out = (float*)d_out;

    char* ws = (char*)d_ws;
    size_t off = 0;
    auto alloc = [&](size_t bytes) {
        size_t o = off;
        off += (bytes + 255) & ~(size_t)255;
        return o;
    };
    float*    d2    = (float*)(ws + alloc((size_t)N_DB * 4));
    float*    x2    = (float*)(ws + alloc((size_t)B_Q * 4));
    int*      idx   = (int*)(ws + alloc((size_t)B_Q * K_NN * 4));
    int*      thr_t = (int*)(ws + alloc((size_t)B_Q * 4));
    int*      cntF  = (int*)(ws + alloc((size_t)B_Q * 4));
    int*      nleF  = (int*)(ws + alloc((size_t)B_Q * 4));
    int*      badF  = (int*)(ws + alloc((size_t)B_Q * 4));
    unsigned char* counts = (unsigned char*)(ws + alloc((size_t)NT * B_Q));
    unsigned char* nle2   = (unsigned char*)(ws + alloc((size_t)NT * B_Q));
    unsigned* cand2 = (unsigned*)(ws + alloc((size_t)NT * B_Q * SLOT * 4));
    float*    cdG   = (float*)(ws + alloc((size_t)B_Q * CAP * 4));
    int*      ciG   = (int*)(ws + alloc((size_t)B_Q * CAP * 4));
    unsigned short* dbb = (unsigned short*)(ws + alloc((size_t)N_DB * 64 * 2));
    unsigned short* inb = (unsigned short*)(ws + alloc((size_t)B_Q * 64 * 2));
    unsigned char*  sbin = (unsigned char*)(ws + alloc((size_t)B_Q * NS));

    hipMemsetAsync(d_out, 0, sizeof(float) * out_size, stream);

    k_prep<<<(N_DB + B_Q + 15) / 16, 256, 0, stream>>>(db_X, input, dbb, inb, d2, x2);
    {
        dim3 g(NS / 128, B_Q / 128);
        k_gemm_sample<<<g, 256, 0, stream>>>(inb, dbb, x2, d2, sbin);
    }
    k_thr<<<B_Q, 256, 0, stream>>>(sbin, thr_t);
    {
        dim3 g(NT, B_Q / 128);
        k_gemm_cand<<<g, 256, 0, stream>>>(inb, dbb, x2, d2, thr_t, counts, nle2, cand2);
    }
    k_refine<<<B_Q, 256, 0, stream>>>(counts, nle2, cand2, input, db_X, x2, d2,
                                      cdG, ciG, cntF, nleF, badF);
    k_rank<<<B_Q, 256, 0, stream>>>(cntF, nleF, badF, cdG, ciG, thr_t,
                                    input, db_X, x2, d2, idx);
    k_regress<<<B_Q, 256, 0, stream>>>(input, target, db_X, db_y, idx, out);
}